// Round 3
// 108.949 us; speedup vs baseline: 1.0582x; 1.0582x over previous
//
#include <hip/hip_runtime.h>
#include <math.h>

#define T_SAMPLES 16384
#define BC 128            // 64 batch * 2 channels
#define NUM_FREQS 257
#define NUM_TIMES 513

// Workspace: fp16 spectra, TRANSPOSED [bc][f][t], row stride padded to %4==0:
//  r0: N=64   F=33  NT=513 NTP=516   r1: N=128  F=65  NT=257 NTP=260
//  r2: N=256  F=129 NT=129 NTP=132   r3: N=512  F=257 NT=65  NTP=68
// offsets in HALF units:
#define OFF0 0
#define OFF1 2179584      // 128*33*516
#define OFF2 4342784      // + 128*65*260
#define OFF3 6522368      // + 128*129*132

typedef float    vf2 __attribute__((ext_vector_type(2)));
typedef float    vf4 __attribute__((ext_vector_type(4)));
typedef vf4 vf4u __attribute__((aligned(4)));   // unaligned-capable float4
typedef _Float16 vh2 __attribute__((ext_vector_type(2)));
typedef _Float16 vh4 __attribute__((ext_vector_type(4)));

// ---------- compile-time trig tables (no runtime sincosf) ----------
constexpr double CPI = 3.14159265358979323846;
constexpr double ctsin(double x) {
    double x2 = x * x, t = x, s = x;
    for (int n = 1; n <= 12; ++n) { t *= -x2 / (double)((2*n) * (2*n + 1)); s += t; }
    return s;
}
constexpr double ctcos(double x) {
    double x2 = x * x, t = 1.0, s = 1.0;
    for (int n = 1; n <= 12; ++n) { t *= -x2 / (double)((2*n - 1) * (2*n)); s += t; }
    return s;
}
struct Tables {
    // lane-major: [lane][0..5]=stage twiddles (hi-folded), [6..8]=tw6..tw8, [9]=pad
    float lane_tw[64][10][2];   // 80 B/lane -> 5 float4 loads
    float win[4][512];          // periodic Hann per resolution (N = 64<<r)
};
constexpr Tables make_tables() {
    Tables T{};
    for (int l = 0; l < 64; ++l) {
        for (int b = 0; b < 6; ++b) {
            const bool hi = (l >> b) & 1;
            const int  k  = l & ((1 << b) - 1);
            const double a = -2.0 * CPI * (double)k / (double)(1 << (b + 1));
            T.lane_tw[l][b][0] = hi ? (float)ctcos(a) : 1.0f;
            T.lane_tw[l][b][1] = hi ? (float)ctsin(a) : 0.0f;
        }
        for (int i = 0; i < 3; ++i) {
            const double a = -2.0 * CPI * (double)l / (double)(128 << i);
            T.lane_tw[l][6 + i][0] = (float)ctcos(a);
            T.lane_tw[l][6 + i][1] = (float)ctsin(a);
        }
        T.lane_tw[l][9][0] = 0.0f; T.lane_tw[l][9][1] = 0.0f;
    }
    for (int r = 0; r < 4; ++r) {
        const int N = 64 << r;
        for (int n = 0; n < N; ++n) {
            const int m = (2 * n <= N) ? n : n - N;
            const double a = 2.0 * CPI * (double)m / (double)N;
            T.win[r][n] = (float)(0.5 - 0.5 * ctcos(a));
        }
    }
    return T;
}
__device__ __constant__ Tables g_tab = make_tables();
// -------------------------------------------------------------------

__device__ inline vf2 cmul(vf2 a, vf2 b) {
    vf2 ar = { -a.y, a.x };
    return b.x * a + b.y * ar;
}

// DPP lane exchange within quads (free quad_perm): 0xB1 = xor1, 0x4E = xor2
template <int CTRL>
__device__ inline float dppf(float x) {
    return __builtin_bit_cast(float,
        __builtin_amdgcn_update_dpp(0, __builtin_bit_cast(int, x),
                                    CTRL, 0xF, 0xF, true));
}

// ds_swizzle xor exchange (bit-mode: and=0x1F, or=0, xor=mask; masks < 32
// stay within each 32-lane half, valid for lane-bits 4..2). These exact
// patterns are the ISA doc's canonical wave-reduce constants.
template <int PAT>
__device__ inline float swzf(float x) {
    return __builtin_bit_cast(float,
        __builtin_amdgcn_ds_swizzle(__builtin_bit_cast(int, x), PAT));
}

// Butterfly stage b=5 (lane^32): __shfl_xor — KNOWN-GOOD baseline path.
// (permlane32_swap experiment shelved: swap-direction semantics unresolved
// after r0/r1; retry as a single-change experiment once the rest is green.)
template <int KL, int RR>
__device__ inline void stage_shfl32(vf2 (&d)[KL][RR], vf2 w, float s) {
#pragma unroll
    for (int q = 0; q < KL; ++q) {
#pragma unroll
        for (int r = 0; r < RR; ++r) {
            vf2 p2;
            p2.x = __shfl_xor(d[q][r].x, 32, 64);
            p2.y = __shfl_xor(d[q][r].y, 32, 64);
            vf2 t  = p2 + d[q][r] * s;
            vf2 tr = { -t.y, t.x };
            d[q][r] = w.x * t + w.y * tr;
        }
    }
}

// Butterfly stages b=4..2 via ds_swizzle (same LDS pipe as ds_bpermute but
// immediate pattern: no per-lane address VGPR setup).
template <int PAT, int KL, int RR>
__device__ inline void stage_swz(vf2 (&d)[KL][RR], vf2 w, float s) {
#pragma unroll
    for (int q = 0; q < KL; ++q) {
#pragma unroll
        for (int r = 0; r < RR; ++r) {
            vf2 p2 = { swzf<PAT>(d[q][r].x), swzf<PAT>(d[q][r].y) };
            vf2 t  = p2 + d[q][r] * s;
            vf2 tr = { -t.y, t.x };
            d[q][r] = w.x * t + w.y * tr;
        }
    }
}

// Packed-real shuffle FFT, batched for ILP: one wave owns KLOOP = P/4
// CONTIGUOUS frame pairs (z = x[2m] + i*x[2m+1]); KLOOP*R == 8 independent
// butterfly chains per wave. DIF: register stages (bits >= 6) in-register;
// lane stage b=5 via shfl_xor, b=4..2 via ds_swizzle, b=1..0 via DPP
// quad_perm. Full Z scattered (bit-reversal resolved) into an interleaved
// float2 LDS buffer (b64 ops, pos = p*RS2 + f + (f>>4), odd RS2 -> bank
// permutation); Hermitian separation fused into a coalesced transposed fp16
// write (X1,X2 per half2).
template <int LOGN, int P>
__device__ void fft_tile_body(const float* __restrict__ x, _Float16* __restrict__ spec,
                              int tile, int bc, vf2* __restrict__ zb) {
    constexpr int N     = 1 << LOGN;
    constexpr int HOP   = N / 2;
    constexpr int F     = HOP + 1;
    constexpr int NT    = T_SAMPLES / HOP + 1;
    constexpr int NTP   = (NT + 3) & ~3;    // padded row stride (halves), %4==0
    constexpr int NPAIR = (NT + 1) / 2;
    constexpr int R     = N / 64;
    constexpr int RS2   = N + N / 16 + 1;   // ODD float2 row stride
    constexpr int KLOOP = P / 4;            // pairs per wave (KLOOP*R == 8)
    const float NORM4   = 0.25f * 8.0f / (3.0f * (float)N);  // 1/(4*sum(w^2))

    const int tid   = threadIdx.x;
    const int lane  = tid & 63;
    const int wave  = tid >> 6;
    const int pair0 = tile * P;
    const int t0    = pair0 * 2;

    // packed table loads: 5 float4 per lane
    float sgn[6];
    vf2   twe[6];
    vf2   tw6 = {1,0}, tw7 = {1,0}, tw8 = {1,0};
    {
        const vf4* twp = (const vf4*)g_tab.lane_tw[lane];
        vf4 A = twp[0], B = twp[1], C = twp[2], D = twp[3], E = twp[4];
        twe[0] = {A.x, A.y}; twe[1] = {A.z, A.w};
        twe[2] = {B.x, B.y}; twe[3] = {B.z, B.w};
        twe[4] = {C.x, C.y}; twe[5] = {C.z, C.w};
        if constexpr (LOGN >= 7) tw6 = {D.x, D.y};
        if constexpr (LOGN >= 8) tw7 = {D.z, D.w};
        if constexpr (LOGN >= 9) tw8 = {E.x, E.y};
#pragma unroll
        for (int b = 0; b < 6; ++b) sgn[b] = ((lane >> b) & 1) ? -1.0f : 1.0f;
    }

    float wr[R];
#pragma unroll
    for (int r = 0; r < R; ++r) wr[r] = g_tab.win[LOGN - 6][r * 64 + lane];

    const float* xb = x + (size_t)bc * T_SAMPLES;

    vf2  d[KLOOP][R];
    bool act[KLOOP];

    // ---- load all pairs up front; contiguous per wave (L1 locality) ----
#pragma unroll
    for (int q = 0; q < KLOOP; ++q) {
        const int p  = wave * KLOOP + q;
        const int pg = pair0 + p;
        act[q] = (pg < NPAIR);
        if (act[q]) {
            const int t1 = 2 * pg, t2 = t1 + 1;
            const bool refl = (t1 == 0) || (t1 * HOP + N - 1 >= T_SAMPLES) || (t2 >= NT);
            if (!refl) {
                const float* src = xb + t1 * HOP - HOP;
#pragma unroll
                for (int r = 0; r < R; ++r) {
                    int n = r * 64 + lane;
                    vf2 v = { src[n], src[n + HOP] };
                    d[q][r] = v * wr[r];
                }
            } else {
#pragma unroll
                for (int r = 0; r < R; ++r) {
                    int n = r * 64 + lane;
                    int g = t1 * HOP + n - HOP;
                    g = (g < 0) ? -g : g;
                    g = (g >= T_SAMPLES) ? (2 * T_SAMPLES - 2 - g) : g;
                    float re = xb[g] * wr[r];
                    float im = 0.0f;
                    if (t2 < NT) {
                        int h = t2 * HOP + n - HOP;
                        h = (h < 0) ? -h : h;
                        h = (h >= T_SAMPLES) ? (2 * T_SAMPLES - 2 - h) : h;
                        im = xb[h] * wr[r];
                    }
                    d[q][r] = { re, im };
                }
            }
        } else {
#pragma unroll
            for (int r = 0; r < R; ++r) d[q][r] = vf2{0.0f, 0.0f};
        }
    }

    // ---- in-register DIF stages (bits 8,7,6), all pairs ----
    if constexpr (LOGN >= 9) {
        const vf2 u8 = { 0.70710678118654752f, -0.70710678118654752f };
#pragma unroll
        for (int q = 0; q < KLOOP; ++q) {
            vf2 tt = tw8;
#pragma unroll
            for (int r = 0; r < 4; ++r) {
                vf2 a = d[q][r], b = d[q][r + 4];
                d[q][r]     = a + b;
                d[q][r + 4] = cmul(a - b, tt);
                tt = cmul(tt, u8);
            }
        }
    }
    if constexpr (LOGN >= 8) {
        const vf2 t0_ = tw7;
        const vf2 t1_ = { tw7.y, -tw7.x };
#pragma unroll
        for (int q = 0; q < KLOOP; ++q) {
#pragma unroll
            for (int g = 0; g < R; g += 4) {
                { vf2 a = d[q][g],   b = d[q][g+2]; d[q][g]   = a + b; d[q][g+2] = cmul(a - b, t0_); }
                { vf2 a = d[q][g+1], b = d[q][g+3]; d[q][g+1] = a + b; d[q][g+3] = cmul(a - b, t1_); }
            }
        }
    }
    if constexpr (LOGN >= 7) {
#pragma unroll
        for (int q = 0; q < KLOOP; ++q) {
#pragma unroll
            for (int g = 0; g < R; g += 2) {
                vf2 a = d[q][g], b = d[q][g+1];
                d[q][g]   = a + b;
                d[q][g+1] = cmul(a - b, tw6);
            }
        }
    }

    // ---- cross-lane stages: b=5 shfl_xor (known-good), b=4..2 ds_swizzle ----
    stage_shfl32(d, twe[5], sgn[5]);
    stage_swz<0x401F>(d, twe[4], sgn[4]);   // xor 16
    stage_swz<0x201F>(d, twe[3], sgn[3]);   // xor 8
    stage_swz<0x101F>(d, twe[2], sgn[2]);   // xor 4
    // ---- b=1: DPP quad_perm xor2 ----
    {
        const vf2   w = twe[1];
        const float s = sgn[1];
#pragma unroll
        for (int q = 0; q < KLOOP; ++q) {
#pragma unroll
            for (int r = 0; r < R; ++r) {
                vf2 p2 = { dppf<0x4E>(d[q][r].x), dppf<0x4E>(d[q][r].y) };
                vf2 t  = p2 + d[q][r] * s;
                vf2 tr = { -t.y, t.x };
                d[q][r] = w.x * t + w.y * tr;
            }
        }
    }
    // ---- b=0: DPP quad_perm xor1, twiddle == 1 ----
    {
        const float s = sgn[0];
#pragma unroll
        for (int q = 0; q < KLOOP; ++q) {
#pragma unroll
            for (int r = 0; r < R; ++r) {
                vf2 p2 = { dppf<0xB1>(d[q][r].x), dppf<0xB1>(d[q][r].y) };
                d[q][r] = p2 + d[q][r] * s;
            }
        }
    }

    // ---- scatter full Z (b64), bit-reversal resolved; (f>>4) swizzle ----
#pragma unroll
    for (int q = 0; q < KLOOP; ++q) {
        if (act[q]) {
            const int p = wave * KLOOP + q;
#pragma unroll
            for (int r = 0; r < R; ++r) {
                int idx = r * 64 + lane;
                int f   = (int)(__brev((unsigned)idx) >> (32 - LOGN));
                zb[p * RS2 + f + (f >> 4)] = d[q][r];
            }
        }
    }
    __syncthreads();

    // Hermitian separation: X1 (t even) + X2 (t odd) from one (Z[f],Z[N-f])
    // b64 read pair, packed into a single aligned half2 store.
    _Float16* sbase = spec + (size_t)bc * F * NTP;
    for (int e = tid; e < F * P; e += 256) {
        int f = e / P;                     // P is a power of two
        int p = e & (P - 1);
        int t = t0 + 2 * p;
        if (t < NT) {                      // matches act: pair0+p < NPAIR
            int fn = (N - f) & (N - 1);
            vf2 A = zb[p * RS2 + f  + (f  >> 4)];
            vf2 B = zb[p * RS2 + fn + (fn >> 4)];
            float rx = A.x + B.x, ry = A.y - B.y;      // X1 = (Z + conj(Zn))/2
            float sx = A.x - B.x, sy = A.y + B.y;      // X2 = (Z - conj(Zn))/2i
            vh2 pv = { (_Float16)((rx * rx + ry * ry) * NORM4),
                       (_Float16)((sx * sx + sy * sy) * NORM4) };   // last col X2 lands in pad
            *(vh2*)(sbase + (size_t)f * NTP + t) = pv;
        }
    }
}

// Fused kernel, uniform 9 tiles per resolution:
// bx in [0,9) N=64 | [9,18) N=128 | [18,27) N=256 | [27,36) N=512
__global__ __launch_bounds__(256) void fft_all_kernel(const float* __restrict__ x,
                                                      _Float16* __restrict__ ws) {
    __shared__ vf2 smem[2208];   // max P*RS2: res0 32*69 = 2208 float2 = 17664 B
    const int bx = blockIdx.x;
    const int bc = blockIdx.y;
    if (bx < 9)        fft_tile_body<6, 32>(x, ws + OFF0, bx,      bc, smem);
    else if (bx < 18)  fft_tile_body<7, 16>(x, ws + OFF1, bx - 9,  bc, smem);
    else if (bx < 27)  fft_tile_body<8, 8> (x, ws + OFF2, bx - 18, bc, smem);
    else               fft_tile_body<9, 4> (x, ws + OFF3, bx - 27, bc, smem);
}

// 2 output rows (i) x 4 columns (j) per thread. Gather compression: across a
// 4-column group the source column index spans <= 2 (r1) / <= 1 (r2, r3), so
// instead of 4 scalar gathers per row/res we load the ENDPOINTS (+1 middle
// for r1) and pick per-column with equality cndmasks: 24 -> 14 scalar loads
// per thread; same cache lines touched, ~40% fewer VMEM instructions.
__global__ __launch_bounds__(256) void remap_max_kernel(const _Float16* __restrict__ ws,
                                                        float* __restrict__ out) {
    const int JG    = 129;                    // ceil(513/4)
    const int IG    = 129;                    // ceil(257/2)
    const int total = BC * IG * JG;
    int idx = blockIdx.x * 256 + threadIdx.x;
    if (idx >= total) return;
    int jg  = idx % JG;
    int rem = idx / JG;
    int ig  = rem % IG;
    int bc  = rem / IG;
    int j0  = jg * 4;
    int i0  = ig * 2;
    const bool fullj = (j0 + 3 < NUM_TIMES);
    const int  ni    = (i0 + 1 < NUM_FREQS) ? 2 : 1;

    float mv[2][4];
#pragma unroll
    for (int ii = 0; ii < 2; ++ii) {
        mv[ii][0] = mv[ii][1] = mv[ii][2] = mv[ii][3] = 0.0f;
        if (ii < ni) {   // r0: ti == j; stride 516, j0 %4==0 -> aligned half4
            int fi = ((i0 + ii) * 33) / NUM_FREQS;
            const _Float16* p = ws + OFF0 + ((size_t)bc * 33 + fi) * 516 + j0;
            if (fullj) {
                vh4 v = *(const vh4*)p;
                mv[ii][0] = (float)v.x; mv[ii][1] = (float)v.y;
                mv[ii][2] = (float)v.z; mv[ii][3] = (float)v.w;
            } else {
                mv[ii][0] = (float)p[0];
            }
        }
    }

    const int fi1a = (i0 * 65) / NUM_FREQS;
    const int fi2a = (i0 * 129) / NUM_FREQS;
    const int fi3a = i0;                      // 257 freqs -> identity
    int fi1b = ((i0 + 1) * 65) / NUM_FREQS;  if (fi1b > 64)  fi1b = 64;
    int fi2b = ((i0 + 1) * 129) / NUM_FREQS; if (fi2b > 128) fi2b = 128;
    int fi3b = i0 + 1;                       if (fi3b > 256) fi3b = 256;

    const _Float16* p1a = ws + OFF1 + ((size_t)bc * 65  + fi1a) * 260;
    const _Float16* p1b = ws + OFF1 + ((size_t)bc * 65  + fi1b) * 260;
    const _Float16* p2a = ws + OFF2 + ((size_t)bc * 129 + fi2a) * 132;
    const _Float16* p2b = ws + OFF2 + ((size_t)bc * 129 + fi2b) * 132;
    const _Float16* p3a = ws + OFF3 + ((size_t)bc * 257 + fi3a) * 68;
    const _Float16* p3b = ws + OFF3 + ((size_t)bc * 257 + fi3b) * 68;

    // source column indices per output column (floor maps)
    int t1[4], t2[4], t3[4];
#pragma unroll
    for (int k = 0; k < 4; ++k) {
        int j = j0 + k;
        t1[k] = (j * 257) / NUM_TIMES;
        t2[k] = (j * 129) / NUM_TIMES;
        t3[k] = (j * 65)  / NUM_TIMES;
    }
    // endpoint gathers (all in-bounds of the padded rows: t1[3] <= 258 < 260,
    // t2[3] <= 129 < 132, t3[3] <= 65 < 68, t1[0]+1 <= 257; pad values are
    // loaded but never selected for valid j)
    float a1A = (float)p1a[t1[0]], m1A = (float)p1a[t1[0] + 1], b1A = (float)p1a[t1[3]];
    float a2A = (float)p2a[t2[0]], b2A = (float)p2a[t2[3]];
    float a3A = (float)p3a[t3[0]], b3A = (float)p3a[t3[3]];
    float a1B = (float)p1b[t1[0]], m1B = (float)p1b[t1[0] + 1], b1B = (float)p1b[t1[3]];
    float a2B = (float)p2b[t2[0]], b2B = (float)p2b[t2[3]];
    float a3B = (float)p3b[t3[0]], b3B = (float)p3b[t3[3]];

#pragma unroll
    for (int k = 0; k < 4; ++k) {
        int j = j0 + k;
        if (j < NUM_TIMES) {
            float v1A = (t1[k] == t1[0]) ? a1A : ((t1[k] == t1[3]) ? b1A : m1A);
            float v2A = (t2[k] == t2[0]) ? a2A : b2A;
            float v3A = (t3[k] == t3[0]) ? a3A : b3A;
            mv[0][k] = fmaxf(mv[0][k], v1A);
            mv[0][k] = fmaxf(mv[0][k], v2A);
            mv[0][k] = fmaxf(mv[0][k], v3A);
            float v1B = (t1[k] == t1[0]) ? a1B : ((t1[k] == t1[3]) ? b1B : m1B);
            float v2B = (t2[k] == t2[0]) ? a2B : b2B;
            float v3B = (t3[k] == t3[0]) ? a3B : b3B;
            mv[1][k] = fmaxf(mv[1][k], v1B);
            mv[1][k] = fmaxf(mv[1][k], v2B);
            mv[1][k] = fmaxf(mv[1][k], v3B);
        }
    }

#pragma unroll
    for (int ii = 0; ii < 2; ++ii) {
        if (ii < ni) {
            float* po = out + ((size_t)bc * NUM_FREQS + i0 + ii) * NUM_TIMES + j0;
            if (fullj) {
                vf4 v = { mv[ii][0], mv[ii][1], mv[ii][2], mv[ii][3] };
                *(vf4u*)po = v;
            } else {
                po[0] = mv[ii][0];
            }
        }
    }
}

extern "C" void kernel_launch(void* const* d_in, const int* in_sizes, int n_in,
                              void* d_out, int out_size, void* d_ws, size_t ws_size,
                              hipStream_t stream) {
    const float* x = (const float*)d_in[0];
    _Float16* ws = (_Float16*)d_ws;
    float* out = (float*)d_out;

    fft_all_kernel<<<dim3(36, BC), 256, 0, stream>>>(x, ws);

    const int total = BC * 129 * 129;
    remap_max_kernel<<<(total + 255) / 256, 256, 0, stream>>>(ws, out);
}